// Round 5
// baseline (17.149 us; speedup 1.0000x reference)
//
#include <hip/hip_runtime.h>

#define NUM_EXPERTS 8
#define FEAT        128
#define NUM_RANKED  10000
#define NBLOCKS     1250   // 4 waves/block * 1250 = 5000 waves; each wave: 2 nodes
                           // ~80 VGPR -> 6 waves/SIMD -> ~1536 blocks resident:
                           // whole grid fits in ONE dispatch round (no tail).

// Per-node decomposition (P = 28 unordered pairs):
//   pair-sum = 0.5 * [ (E-1)*SA - Sum_d( Sw[d]*Slp[d] - Swlp[d] ) ]
// with per gathered row: p = softmax, lp = log_softmax, w = exp(p)
//   SA = Sum_{e,d} w*p,  Sw[d] = Sum_e w,  Slp[d] = Sum_e lp,  Swlp[d] = Sum_e w*lp
//
// Wave layout: half-wave per row-parity. lane = 32*half + sl.
//   lane loads float4 of dims [4*sl, 4*sl+4) for rows {2i+half}, i=0..3.
//   -> 4 x 16B/lane loads, width-32 row reductions (5 shfl steps),
//      one shfl_xor(32) pass merges cross-row per-dim sums across halves.
// (Body math verified rounds 2-4, absmax 0.0.)
__device__ __forceinline__ float node_val(const float* __restrict__ xo,
                                          const int* __restrict__ rankings,
                                          const int* __restrict__ nodes,
                                          int s, int half, int sl) {
  const int node = nodes[s];
  const float* base = xo + (size_t)node * (NUM_EXPERTS * FEAT);

  const int4 ra = *reinterpret_cast<const int4*>(rankings + s * NUM_EXPERTS);
  const int4 rb = *reinterpret_cast<const int4*>(rankings + s * NUM_EXPERTS + 4);

  const int r0 = half ? ra.y : ra.x;
  const int r1 = half ? ra.w : ra.z;
  const int r2 = half ? rb.y : rb.x;
  const int r3 = half ? rb.w : rb.z;

  float4 v[4];
  v[0] = *reinterpret_cast<const float4*>(base + r0 * FEAT + sl * 4);
  v[1] = *reinterpret_cast<const float4*>(base + r1 * FEAT + sl * 4);
  v[2] = *reinterpret_cast<const float4*>(base + r2 * FEAT + sl * 4);
  v[3] = *reinterpret_cast<const float4*>(base + r3 * FEAT + sl * 4);

  float m[4];
#pragma unroll
  for (int i = 0; i < 4; ++i)
    m[i] = fmaxf(fmaxf(v[i].x, v[i].y), fmaxf(v[i].z, v[i].w));
#pragma unroll
  for (int o = 16; o >= 1; o >>= 1) {
#pragma unroll
    for (int i = 0; i < 4; ++i) m[i] = fmaxf(m[i], __shfl_xor(m[i], o));
  }

  float4 ex[4];
  float ssum[4];
#pragma unroll
  for (int i = 0; i < 4; ++i) {
    ex[i].x = __expf(v[i].x - m[i]);
    ex[i].y = __expf(v[i].y - m[i]);
    ex[i].z = __expf(v[i].z - m[i]);
    ex[i].w = __expf(v[i].w - m[i]);
    ssum[i] = (ex[i].x + ex[i].y) + (ex[i].z + ex[i].w);
  }
#pragma unroll
  for (int o = 16; o >= 1; o >>= 1) {
#pragma unroll
    for (int i = 0; i < 4; ++i) ssum[i] += __shfl_xor(ssum[i], o);
  }

  float4 sw = {0, 0, 0, 0}, slp = {0, 0, 0, 0}, swlp = {0, 0, 0, 0};
  float sa = 0.f;
#pragma unroll
  for (int i = 0; i < 4; ++i) {
    const float inv = 1.0f / ssum[i];
    const float lse = __logf(ssum[i]);
    const float lp0 = v[i].x - m[i] - lse, lp1 = v[i].y - m[i] - lse;
    const float lp2 = v[i].z - m[i] - lse, lp3 = v[i].w - m[i] - lse;
    const float p0 = ex[i].x * inv, p1 = ex[i].y * inv;
    const float p2 = ex[i].z * inv, p3 = ex[i].w * inv;
    const float w0 = __expf(p0), w1 = __expf(p1);
    const float w2 = __expf(p2), w3 = __expf(p3);
    sa += (w0 * p0 + w1 * p1) + (w2 * p2 + w3 * p3);
    sw.x += w0;  sw.y += w1;  sw.z += w2;  sw.w += w3;
    slp.x += lp0; slp.y += lp1; slp.z += lp2; slp.w += lp3;
    swlp.x += w0 * lp0; swlp.y += w1 * lp1; swlp.z += w2 * lp2; swlp.w += w3 * lp3;
  }

  // merge cross-row per-dim sums across halves (dim d lives at sl and sl+32)
  sw.x += __shfl_xor(sw.x, 32);   sw.y += __shfl_xor(sw.y, 32);
  sw.z += __shfl_xor(sw.z, 32);   sw.w += __shfl_xor(sw.w, 32);
  slp.x += __shfl_xor(slp.x, 32); slp.y += __shfl_xor(slp.y, 32);
  slp.z += __shfl_xor(slp.z, 32); slp.w += __shfl_xor(slp.w, 32);
  swlp.x += __shfl_xor(swlp.x, 32); swlp.y += __shfl_xor(swlp.y, 32);
  swlp.z += __shfl_xor(swlp.z, 32); swlp.w += __shfl_xor(swlp.w, 32);

  // both halves hold identical cross terms for their dims -> count 0.5x
  const float cross = (sw.x * slp.x - swlp.x) + (sw.y * slp.y - swlp.y) +
                      (sw.z * slp.z - swlp.z) + (sw.w * slp.w - swlp.w);
  float val = 7.0f * sa - 0.5f * cross;
#pragma unroll
  for (int o = 32; o >= 1; o >>= 1) val += __shfl_xor(val, o);
  return val;
}

__global__ __launch_bounds__(256) void ecl_main(const float* __restrict__ xo,
                                               const int* __restrict__ rankings,
                                               const int* __restrict__ nodes,
                                               double* __restrict__ partial) {
  const int lane = threadIdx.x & 63;
  const int half = lane >> 5;
  const int sl   = lane & 31;
  const int wid  = (blockIdx.x * blockDim.x + threadIdx.x) >> 6;  // 0..4999

  double acc = 0.0;
#pragma unroll
  for (int t = 0; t < 2; ++t) {
    const float val = node_val(xo, rankings, nodes, wid * 2 + t, half, sl);
    acc += 0.5 * (double)val;
  }

  __shared__ double wsum[4];
  if (lane == 0) wsum[threadIdx.x >> 6] = acc;
  __syncthreads();
  if (threadIdx.x == 0)
    partial[blockIdx.x] = (wsum[0] + wsum[1]) + (wsum[2] + wsum[3]);
}

__global__ __launch_bounds__(256) void ecl_reduce(const double* __restrict__ partial,
                                                  float* __restrict__ out) {
  // 5 independent loads per thread (1250 = 256*4 + 226), one waitcnt, tree sum.
  double t[5];
#pragma unroll
  for (int k = 0; k < 5; ++k) {
    const int i = threadIdx.x + 256 * k;
    t[k] = (i < NBLOCKS) ? partial[i] : 0.0;
  }
  double a = ((t[0] + t[1]) + (t[2] + t[3])) + t[4];
  __shared__ double lds[256];
  lds[threadIdx.x] = a;
  __syncthreads();
  for (int st = 128; st >= 1; st >>= 1) {
    if (threadIdx.x < st) lds[threadIdx.x] += lds[threadIdx.x + st];
    __syncthreads();
  }
  if (threadIdx.x == 0) {
    const double scale = 0.1 / ((double)NUM_RANKED * 28.0);  // BETA / (S*P)
    out[0] = (float)(lds[0] * scale);
  }
}

extern "C" void kernel_launch(void* const* d_in, const int* in_sizes, int n_in,
                              void* d_out, int out_size, void* d_ws, size_t ws_size,
                              hipStream_t stream) {
  const float* expert_outputs = (const float*)d_in[0];
  const int*   rankings       = (const int*)d_in[1];
  const int*   node_indices   = (const int*)d_in[2];
  float* out = (float*)d_out;
  double* partial = (double*)d_ws;  // 1250 doubles

  ecl_main<<<NBLOCKS, 256, 0, stream>>>(expert_outputs, rankings, node_indices, partial);
  ecl_reduce<<<1, 256, 0, stream>>>(partial, out);
}

// Round 6
// 16.399 us; speedup vs baseline: 1.0457x; 1.0457x over previous
//
#include <hip/hip_runtime.h>

#define NUM_EXPERTS 8
#define FEAT        128
#define NUM_RANKED  10000
#define NBLOCKS     2500   // 4 waves/block, 1 wave per ranked node (R4 config — best so far)

// Per-node decomposition (P = 28 unordered pairs):
//   pair-sum = 0.5 * [ (E-1)*SA - Sum_d( Sw[d]*Slp[d] - Swlp[d] ) ]
// with per gathered row: p = softmax, lp = log_softmax, w = exp(p)
//   SA = Sum_{e,d} w*p,  Sw[d] = Sum_e w,  Slp[d] = Sum_e lp,  Swlp[d] = Sum_e w*lp
//
// Wave layout: half-wave per row-parity. lane = 32*half + sl.
//   lane loads float4 of dims [4*sl, 4*sl+4) for rows {2i+half}, i=0..3.
// Scalarization: s, nodes[s], rankings[s][0..7] are wave-uniform ->
//   readfirstlane forces SGPR, compiler emits s_load + SGPR-base gathers.
__global__ __launch_bounds__(256) void ecl_main(const float* __restrict__ xo,
                                               const int* __restrict__ rankings,
                                               const int* __restrict__ nodes,
                                               double* __restrict__ partial) {
  const int lane = threadIdx.x & 63;
  const int half = lane >> 5;
  const int sl   = lane & 31;
  int s = (blockIdx.x * blockDim.x + threadIdx.x) >> 6;  // wave-uniform by construction
  s = __builtin_amdgcn_readfirstlane(s);

  const int node = __builtin_amdgcn_readfirstlane(nodes[s]);
  const float* base = xo + (size_t)node * (NUM_EXPERTS * FEAT);

  const int q0 = __builtin_amdgcn_readfirstlane(rankings[s * NUM_EXPERTS + 0]);
  const int q1 = __builtin_amdgcn_readfirstlane(rankings[s * NUM_EXPERTS + 1]);
  const int q2 = __builtin_amdgcn_readfirstlane(rankings[s * NUM_EXPERTS + 2]);
  const int q3 = __builtin_amdgcn_readfirstlane(rankings[s * NUM_EXPERTS + 3]);
  const int q4 = __builtin_amdgcn_readfirstlane(rankings[s * NUM_EXPERTS + 4]);
  const int q5 = __builtin_amdgcn_readfirstlane(rankings[s * NUM_EXPERTS + 5]);
  const int q6 = __builtin_amdgcn_readfirstlane(rankings[s * NUM_EXPERTS + 6]);
  const int q7 = __builtin_amdgcn_readfirstlane(rankings[s * NUM_EXPERTS + 7]);

  // rows for this half (one v_cndmask each; address = SGPR base + VGPR offset)
  const int r0 = half ? q1 : q0;
  const int r1 = half ? q3 : q2;
  const int r2 = half ? q5 : q4;
  const int r3 = half ? q7 : q6;

  float4 v[4];
  v[0] = *reinterpret_cast<const float4*>(base + r0 * FEAT + sl * 4);
  v[1] = *reinterpret_cast<const float4*>(base + r1 * FEAT + sl * 4);
  v[2] = *reinterpret_cast<const float4*>(base + r2 * FEAT + sl * 4);
  v[3] = *reinterpret_cast<const float4*>(base + r3 * FEAT + sl * 4);

  float m[4];
#pragma unroll
  for (int i = 0; i < 4; ++i)
    m[i] = fmaxf(fmaxf(v[i].x, v[i].y), fmaxf(v[i].z, v[i].w));
#pragma unroll
  for (int o = 16; o >= 1; o >>= 1) {
#pragma unroll
    for (int i = 0; i < 4; ++i) m[i] = fmaxf(m[i], __shfl_xor(m[i], o));
  }

  float4 ex[4];
  float ssum[4];
#pragma unroll
  for (int i = 0; i < 4; ++i) {
    ex[i].x = __expf(v[i].x - m[i]);
    ex[i].y = __expf(v[i].y - m[i]);
    ex[i].z = __expf(v[i].z - m[i]);
    ex[i].w = __expf(v[i].w - m[i]);
    ssum[i] = (ex[i].x + ex[i].y) + (ex[i].z + ex[i].w);
  }
#pragma unroll
  for (int o = 16; o >= 1; o >>= 1) {
#pragma unroll
    for (int i = 0; i < 4; ++i) ssum[i] += __shfl_xor(ssum[i], o);
  }

  float4 sw = {0, 0, 0, 0}, slp = {0, 0, 0, 0}, swlp = {0, 0, 0, 0};
  float sa = 0.f;
#pragma unroll
  for (int i = 0; i < 4; ++i) {
    const float inv = 1.0f / ssum[i];
    const float lse = __logf(ssum[i]);
    const float lp0 = v[i].x - m[i] - lse, lp1 = v[i].y - m[i] - lse;
    const float lp2 = v[i].z - m[i] - lse, lp3 = v[i].w - m[i] - lse;
    const float p0 = ex[i].x * inv, p1 = ex[i].y * inv;
    const float p2 = ex[i].z * inv, p3 = ex[i].w * inv;
    const float w0 = __expf(p0), w1 = __expf(p1);
    const float w2 = __expf(p2), w3 = __expf(p3);
    sa += (w0 * p0 + w1 * p1) + (w2 * p2 + w3 * p3);
    sw.x += w0;  sw.y += w1;  sw.z += w2;  sw.w += w3;
    slp.x += lp0; slp.y += lp1; slp.z += lp2; slp.w += lp3;
    swlp.x += w0 * lp0; swlp.y += w1 * lp1; swlp.z += w2 * lp2; swlp.w += w3 * lp3;
  }

  // merge cross-row per-dim sums across halves (dim d lives at sl and sl+32)
  sw.x += __shfl_xor(sw.x, 32);   sw.y += __shfl_xor(sw.y, 32);
  sw.z += __shfl_xor(sw.z, 32);   sw.w += __shfl_xor(sw.w, 32);
  slp.x += __shfl_xor(slp.x, 32); slp.y += __shfl_xor(slp.y, 32);
  slp.z += __shfl_xor(slp.z, 32); slp.w += __shfl_xor(slp.w, 32);
  swlp.x += __shfl_xor(swlp.x, 32); swlp.y += __shfl_xor(swlp.y, 32);
  swlp.z += __shfl_xor(swlp.z, 32); swlp.w += __shfl_xor(swlp.w, 32);

  // both halves hold identical cross terms for their dims -> count 0.5x
  const float cross = (sw.x * slp.x - swlp.x) + (sw.y * slp.y - swlp.y) +
                      (sw.z * slp.z - swlp.z) + (sw.w * slp.w - swlp.w);
  float val = 7.0f * sa - 0.5f * cross;
#pragma unroll
  for (int o = 32; o >= 1; o >>= 1) val += __shfl_xor(val, o);

  __shared__ double wsum[4];
  if (lane == 0) wsum[threadIdx.x >> 6] = 0.5 * (double)val;
  __syncthreads();
  if (threadIdx.x == 0)
    partial[blockIdx.x] = (wsum[0] + wsum[1]) + (wsum[2] + wsum[3]);
}

__global__ __launch_bounds__(256) void ecl_reduce(const double* __restrict__ partial,
                                                  float* __restrict__ out) {
  // 10 independent loads per thread (2500 = 256*9 + 196), one waitcnt, tree sum.
  double t[10];
#pragma unroll
  for (int k = 0; k < 10; ++k) {
    const int i = threadIdx.x + 256 * k;
    t[k] = (i < NBLOCKS) ? partial[i] : 0.0;
  }
  double a = ((t[0] + t[1]) + (t[2] + t[3])) + ((t[4] + t[5]) + (t[6] + t[7])) +
             (t[8] + t[9]);
  __shared__ double lds[256];
  lds[threadIdx.x] = a;
  __syncthreads();
  for (int st = 128; st >= 1; st >>= 1) {
    if (threadIdx.x < st) lds[threadIdx.x] += lds[threadIdx.x + st];
    __syncthreads();
  }
  if (threadIdx.x == 0) {
    const double scale = 0.1 / ((double)NUM_RANKED * 28.0);  // BETA / (S*P)
    out[0] = (float)(lds[0] * scale);
  }
}

extern "C" void kernel_launch(void* const* d_in, const int* in_sizes, int n_in,
                              void* d_out, int out_size, void* d_ws, size_t ws_size,
                              hipStream_t stream) {
  const float* expert_outputs = (const float*)d_in[0];
  const int*   rankings       = (const int*)d_in[1];
  const int*   node_indices   = (const int*)d_in[2];
  float* out = (float*)d_out;
  double* partial = (double*)d_ws;  // 2500 doubles

  ecl_main<<<NBLOCKS, 256, 0, stream>>>(expert_outputs, rankings, node_indices, partial);
  ecl_reduce<<<1, 256, 0, stream>>>(partial, out);
}

// Round 7
// 16.392 us; speedup vs baseline: 1.0462x; 1.0004x over previous
//
#include <hip/hip_runtime.h>

#define NUM_EXPERTS 8
#define FEAT        128
#define NUM_RANKED  10000
#define NBLOCKS     1250   // 8 waves/block * 1250 = 10000 waves, 1 wave per node

// Per-node decomposition (P = 28 unordered pairs):
//   pair-sum = 0.5 * [ (E-1)*SA - Sum_d( Sw[d]*Slp[d] - Swlp[d] ) ]
// with per gathered row: p = softmax, lp = log_softmax, w = exp(p)
//   SA = Sum_{e,d} w*p,  Sw[d] = Sum_e w,  Slp[d] = Sum_e lp,  Swlp[d] = Sum_e w*lp
//
// Wave layout: half-wave per row-parity. lane = 32*half + sl.
//   lane loads float4 of dims [4*sl, 4*sl+4) for rows {2i+half}, i=0..3.
// Scalarized wave-uniform index path (readfirstlane -> s_load + SGPR-base gathers).
// (Wave math verified rounds 2-6, absmax 0.0. This round: 512-thread blocks to
//  halve workgroup dispatch count; reduce reads 1250 partials.)
__global__ __launch_bounds__(512) void ecl_main(const float* __restrict__ xo,
                                               const int* __restrict__ rankings,
                                               const int* __restrict__ nodes,
                                               double* __restrict__ partial) {
  const int lane = threadIdx.x & 63;
  const int half = lane >> 5;
  const int sl   = lane & 31;
  int s = (blockIdx.x * blockDim.x + threadIdx.x) >> 6;  // wave-uniform by construction
  s = __builtin_amdgcn_readfirstlane(s);

  const int node = __builtin_amdgcn_readfirstlane(nodes[s]);
  const float* base = xo + (size_t)node * (NUM_EXPERTS * FEAT);

  const int q0 = __builtin_amdgcn_readfirstlane(rankings[s * NUM_EXPERTS + 0]);
  const int q1 = __builtin_amdgcn_readfirstlane(rankings[s * NUM_EXPERTS + 1]);
  const int q2 = __builtin_amdgcn_readfirstlane(rankings[s * NUM_EXPERTS + 2]);
  const int q3 = __builtin_amdgcn_readfirstlane(rankings[s * NUM_EXPERTS + 3]);
  const int q4 = __builtin_amdgcn_readfirstlane(rankings[s * NUM_EXPERTS + 4]);
  const int q5 = __builtin_amdgcn_readfirstlane(rankings[s * NUM_EXPERTS + 5]);
  const int q6 = __builtin_amdgcn_readfirstlane(rankings[s * NUM_EXPERTS + 6]);
  const int q7 = __builtin_amdgcn_readfirstlane(rankings[s * NUM_EXPERTS + 7]);

  const int r0 = half ? q1 : q0;
  const int r1 = half ? q3 : q2;
  const int r2 = half ? q5 : q4;
  const int r3 = half ? q7 : q6;

  float4 v[4];
  v[0] = *reinterpret_cast<const float4*>(base + r0 * FEAT + sl * 4);
  v[1] = *reinterpret_cast<const float4*>(base + r1 * FEAT + sl * 4);
  v[2] = *reinterpret_cast<const float4*>(base + r2 * FEAT + sl * 4);
  v[3] = *reinterpret_cast<const float4*>(base + r3 * FEAT + sl * 4);

  float m[4];
#pragma unroll
  for (int i = 0; i < 4; ++i)
    m[i] = fmaxf(fmaxf(v[i].x, v[i].y), fmaxf(v[i].z, v[i].w));
#pragma unroll
  for (int o = 16; o >= 1; o >>= 1) {
#pragma unroll
    for (int i = 0; i < 4; ++i) m[i] = fmaxf(m[i], __shfl_xor(m[i], o));
  }

  float4 ex[4];
  float ssum[4];
#pragma unroll
  for (int i = 0; i < 4; ++i) {
    ex[i].x = __expf(v[i].x - m[i]);
    ex[i].y = __expf(v[i].y - m[i]);
    ex[i].z = __expf(v[i].z - m[i]);
    ex[i].w = __expf(v[i].w - m[i]);
    ssum[i] = (ex[i].x + ex[i].y) + (ex[i].z + ex[i].w);
  }
#pragma unroll
  for (int o = 16; o >= 1; o >>= 1) {
#pragma unroll
    for (int i = 0; i < 4; ++i) ssum[i] += __shfl_xor(ssum[i], o);
  }

  float4 sw = {0, 0, 0, 0}, slp = {0, 0, 0, 0}, swlp = {0, 0, 0, 0};
  float sa = 0.f;
#pragma unroll
  for (int i = 0; i < 4; ++i) {
    const float inv = 1.0f / ssum[i];
    const float lse = __logf(ssum[i]);
    const float lp0 = v[i].x - m[i] - lse, lp1 = v[i].y - m[i] - lse;
    const float lp2 = v[i].z - m[i] - lse, lp3 = v[i].w - m[i] - lse;
    const float p0 = ex[i].x * inv, p1 = ex[i].y * inv;
    const float p2 = ex[i].z * inv, p3 = ex[i].w * inv;
    const float w0 = __expf(p0), w1 = __expf(p1);
    const float w2 = __expf(p2), w3 = __expf(p3);
    sa += (w0 * p0 + w1 * p1) + (w2 * p2 + w3 * p3);
    sw.x += w0;  sw.y += w1;  sw.z += w2;  sw.w += w3;
    slp.x += lp0; slp.y += lp1; slp.z += lp2; slp.w += lp3;
    swlp.x += w0 * lp0; swlp.y += w1 * lp1; swlp.z += w2 * lp2; swlp.w += w3 * lp3;
  }

  // merge cross-row per-dim sums across halves (dim d lives at sl and sl+32)
  sw.x += __shfl_xor(sw.x, 32);   sw.y += __shfl_xor(sw.y, 32);
  sw.z += __shfl_xor(sw.z, 32);   sw.w += __shfl_xor(sw.w, 32);
  slp.x += __shfl_xor(slp.x, 32); slp.y += __shfl_xor(slp.y, 32);
  slp.z += __shfl_xor(slp.z, 32); slp.w += __shfl_xor(slp.w, 32);
  swlp.x += __shfl_xor(swlp.x, 32); swlp.y += __shfl_xor(swlp.y, 32);
  swlp.z += __shfl_xor(swlp.z, 32); swlp.w += __shfl_xor(swlp.w, 32);

  // both halves hold identical cross terms for their dims -> count 0.5x
  const float cross = (sw.x * slp.x - swlp.x) + (sw.y * slp.y - swlp.y) +
                      (sw.z * slp.z - swlp.z) + (sw.w * slp.w - swlp.w);
  float val = 7.0f * sa - 0.5f * cross;
#pragma unroll
  for (int o = 32; o >= 1; o >>= 1) val += __shfl_xor(val, o);

  __shared__ double wsum[8];
  if (lane == 0) wsum[threadIdx.x >> 6] = 0.5 * (double)val;
  __syncthreads();
  if (threadIdx.x == 0)
    partial[blockIdx.x] = ((wsum[0] + wsum[1]) + (wsum[2] + wsum[3])) +
                          ((wsum[4] + wsum[5]) + (wsum[6] + wsum[7]));
}

__global__ __launch_bounds__(256) void ecl_reduce(const double* __restrict__ partial,
                                                  float* __restrict__ out) {
  // 5 independent loads per thread (1250 = 256*4 + 226), one waitcnt, tree sum.
  double t[5];
#pragma unroll
  for (int k = 0; k < 5; ++k) {
    const int i = threadIdx.x + 256 * k;
    t[k] = (i < NBLOCKS) ? partial[i] : 0.0;
  }
  double a = ((t[0] + t[1]) + (t[2] + t[3])) + t[4];
  __shared__ double lds[256];
  lds[threadIdx.x] = a;
  __syncthreads();
  for (int st = 128; st >= 1; st >>= 1) {
    if (threadIdx.x < st) lds[threadIdx.x] += lds[threadIdx.x + st];
    __syncthreads();
  }
  if (threadIdx.x == 0) {
    const double scale = 0.1 / ((double)NUM_RANKED * 28.0);  // BETA / (S*P)
    out[0] = (float)(lds[0] * scale);
  }
}

extern "C" void kernel_launch(void* const* d_in, const int* in_sizes, int n_in,
                              void* d_out, int out_size, void* d_ws, size_t ws_size,
                              hipStream_t stream) {
  const float* expert_outputs = (const float*)d_in[0];
  const int*   rankings       = (const int*)d_in[1];
  const int*   node_indices   = (const int*)d_in[2];
  float* out = (float*)d_out;
  double* partial = (double*)d_ws;  // 1250 doubles

  ecl_main<<<NBLOCKS, 512, 0, stream>>>(expert_outputs, rankings, node_indices, partial);
  ecl_reduce<<<1, 256, 0, stream>>>(partial, out);
}